// Round 3
// baseline (338.200 us; speedup 1.0000x reference)
//
#include <hip/hip_runtime.h>
#include <hip/hip_bf16.h>
#include <math.h>

#define N_PTS 8192
#define KNN 8
#define JSPLIT 8
#define WAVES 4                    // waves per topk block
#define IB_BLOCK (WAVES * 16)      // 64 query rows per block
#define JCHUNK (N_PTS / JSPLIT)    // 1024 candidates per (wave, js)

typedef __attribute__((ext_vector_type(8))) short bf16x8;
typedef __attribute__((ext_vector_type(4))) float f32x4;

// Sorted top-8 insert: d[0..7] ascending; fully unrolled -> registers only.
__device__ __forceinline__ void insert8(float dv, int iv, float (&d)[8], int (&idx)[8]) {
    if (dv < d[7]) {
        d[7] = dv; idx[7] = iv;
#pragma unroll
        for (int k = 7; k > 0; --k) {
            if (d[k] < d[k - 1]) {
                float td = d[k - 1]; d[k - 1] = d[k]; d[k] = td;
                int ti = idx[k - 1]; idx[k - 1] = idx[k]; idx[k] = ti;
            }
        }
    }
}

// Fused prep: one wave per row. Exact fp32 row-norm + bf16 conversion.
template <int D>
__global__ __launch_bounds__(256) void prep_kernel(const float* __restrict__ x,
                                                   __hip_bfloat16* __restrict__ xb,
                                                   float* __restrict__ sq) {
    const int row = (blockIdx.x * 256 + threadIdx.x) >> 6;
    const int lane = threadIdx.x & 63;
    float s = 0.f;
    if constexpr (D == 128) {
        float2 v = *reinterpret_cast<const float2*>(x + (size_t)row * D + lane * 2);
        s = fmaf(v.x, v.x, v.y * v.y);
        __hip_bfloat162 h = __float22bfloat162_rn(v);
        *reinterpret_cast<__hip_bfloat162*>(xb + (size_t)row * D + lane * 2) = h;
    } else {
        float v = (lane < D) ? x[(size_t)row * D + lane] : 0.f;
        s = v * v;
        if (lane < D) xb[(size_t)row * D + lane] = __float2bfloat16(v);
    }
#pragma unroll
    for (int o = 32; o > 0; o >>= 1) s += __shfl_down(s, o);
    if (lane == 0) sq[row] = s;
}

// MFMA top-8: each wave owns a 16-query tile (B operand, resident in VGPRs)
// and streams 16-candidate j-tiles (A operand). C layout (16x16x32 bf16):
// col = lane&15 (query i), row = (lane>>4)*4 + reg (candidate j).
// Per-lane insert8 over its 4 candidates; 4 lanes per column merged via LDS.
template <int D>
__global__ __launch_bounds__(256, 2) void topk_mfma(const __hip_bfloat16* __restrict__ xb,
                                                    const float* __restrict__ sq,
                                                    float* __restrict__ pd,
                                                    int* __restrict__ pi) {
    constexpr int KB = D / 32;  // 32-wide k blocks per dot product
    const int lane = threadIdx.x & 63;
    const int w = __builtin_amdgcn_readfirstlane((int)(threadIdx.x >> 6));
    const int ib = blockIdx.x * IB_BLOCK + w * 16;  // wave's query-tile base
    const int js = blockIdx.y;
    const int jbase = js * JCHUNK;

    const int lrow = lane & 15;        // A row / B col within tile
    const int lk = (lane >> 4) * 8;    // k offset within 32-k block
    const int jr = (lane >> 4) * 4;    // C row group

    // Query-tile B fragments (held across the whole j loop).
    bf16x8 bfrag[KB];
#pragma unroll
    for (int kb = 0; kb < KB; ++kb)
        bfrag[kb] = *reinterpret_cast<const bf16x8*>(xb + (size_t)(ib + lrow) * D + kb * 32 + lk);

    float d8[8]; int i8[8];
#pragma unroll
    for (int k = 0; k < 8; ++k) { d8[k] = __builtin_inff(); i8[k] = -1; }

#pragma unroll 2
    for (int jt = jbase; jt < jbase + JCHUNK; jt += 16) {
        f32x4 acc = {0.f, 0.f, 0.f, 0.f};
#pragma unroll
        for (int kb = 0; kb < KB; ++kb) {
            bf16x8 afrag = *reinterpret_cast<const bf16x8*>(xb + (size_t)(jt + lrow) * D + kb * 32 + lk);
            acc = __builtin_amdgcn_mfma_f32_16x16x32_bf16(afrag, bfrag[kb], acc, 0, 0, 0);
        }
        // dist(j, i) = sq[j] - 2*dot  (sq[i] dropped: row-constant, order-safe)
        f32x4 sq4 = *reinterpret_cast<const f32x4*>(sq + jt + jr);
        if (jt == ib) {  // diagonal tile: mask self (wave-uniform branch)
#pragma unroll
            for (int r = 0; r < 4; ++r) {
                const int j = jt + jr + r;
                float dist = fmaf(-2.f, acc[r], sq4[r]);
                if (j == ib + lrow) dist = __builtin_inff();
                insert8(dist, j, d8, i8);
            }
        } else {
#pragma unroll
            for (int r = 0; r < 4; ++r) {
                float dist = fmaf(-2.f, acc[r], sq4[r]);
                insert8(dist, jt + jr + r, d8, i8);
            }
        }
    }

    // Merge the 4 lanes holding each column: lanes {i, i+16, i+32, i+48}.
    __shared__ float lds_d[WAVES][64][8];
    __shared__ int lds_i[WAVES][64][8];
#pragma unroll
    for (int k = 0; k < 8; ++k) { lds_d[w][lane][k] = d8[k]; lds_i[w][lane][k] = i8[k]; }
    __syncthreads();
    if (lane < 16) {
        float e[8]; int f[8];
#pragma unroll
        for (int k = 0; k < 8; ++k) { e[k] = __builtin_inff(); f[k] = -1; }
#pragma unroll
        for (int p = 0; p < 4; ++p)
#pragma unroll
            for (int k = 0; k < 8; ++k) insert8(lds_d[w][p * 16 + lane][k], lds_i[w][p * 16 + lane][k], e, f);
        const size_t o = ((size_t)(ib + lane) * JSPLIT + js) * 8;
#pragma unroll
        for (int k = 0; k < 8; ++k) { pd[o + k] = e[k]; pi[o + k] = f[k]; }
    }
}

// Merge JSPLIT partial lists per row for X and Z; count index-set matches.
// Per-block partial sums (no atomics, no zero kernel).
__global__ __launch_bounds__(256) void count_kernel(const float* __restrict__ pdX,
                                                    const int* __restrict__ piX,
                                                    const float* __restrict__ pdZ,
                                                    const int* __restrict__ piZ,
                                                    int* __restrict__ partial) {
    const int row = blockIdx.x * 256 + threadIdx.x;
    float dx[8]; int xi[8];
    float dz[8]; int zi[8];
#pragma unroll
    for (int k = 0; k < 8; ++k) { dx[k] = __builtin_inff(); xi[k] = -1; dz[k] = __builtin_inff(); zi[k] = -2; }
    const size_t base = (size_t)row * (JSPLIT * 8);
    for (int l = 0; l < JSPLIT * 8; ++l) insert8(pdX[base + l], piX[base + l], dx, xi);
    for (int l = 0; l < JSPLIT * 8; ++l) insert8(pdZ[base + l], piZ[base + l], dz, zi);
    int c = 0;
#pragma unroll
    for (int a = 0; a < 8; ++a)
#pragma unroll
        for (int b = 0; b < 8; ++b) c += (xi[a] == zi[b]) ? 1 : 0;
#pragma unroll
    for (int o = 32; o > 0; o >>= 1) c += __shfl_down(c, o);
    __shared__ int wsum[4];
    if ((threadIdx.x & 63) == 0) wsum[threadIdx.x >> 6] = c;
    __syncthreads();
    if (threadIdx.x == 0) partial[blockIdx.x] = wsum[0] + wsum[1] + wsum[2] + wsum[3];
}

__global__ void finalize_kernel(const int* __restrict__ partial, float* __restrict__ out) {
    int v = (threadIdx.x < N_PTS / 256) ? partial[threadIdx.x] : 0;
#pragma unroll
    for (int o = 32; o > 0; o >>= 1) v += __shfl_down(v, o);
    if (threadIdx.x == 0) {
        // loss = 100 * (2*K*N - 2*matches) / N^2  (exact in double)
        double m = (double)v;
        out[0] = (float)((2.0 * KNN * N_PTS - 2.0 * m) * 100.0 / ((double)N_PTS * (double)N_PTS));
    }
}

extern "C" void kernel_launch(void* const* d_in, const int* in_sizes, int n_in,
                              void* d_out, int out_size, void* d_ws, size_t ws_size,
                              hipStream_t stream) {
    const float* X = (const float*)d_in[0];  // 8192 x 128
    const float* Z = (const float*)d_in[1];  // 8192 x 32
    float* out = (float*)d_out;
    char* ws = (char*)d_ws;

    __hip_bfloat16* bX = (__hip_bfloat16*)(ws);                 // 2 MB
    __hip_bfloat16* bZ = (__hip_bfloat16*)(ws + 2097152);       // 512 KB
    float* sqX = (float*)(ws + 2621440);                        // 32 KB
    float* sqZ = (float*)(ws + 2654208);                        // 32 KB
    float* pdX = (float*)(ws + 2686976);                        // 2 MB
    int* piX = (int*)(ws + 4784128);                            // 2 MB
    float* pdZ = (float*)(ws + 6881280);                        // 2 MB
    int* piZ = (int*)(ws + 8978432);                            // 2 MB
    int* partial = (int*)(ws + 11075584);                       // 128 B

    prep_kernel<128><<<N_PTS / 4, 256, 0, stream>>>(X, bX, sqX);
    prep_kernel<32><<<N_PTS / 4, 256, 0, stream>>>(Z, bZ, sqZ);
    topk_mfma<128><<<dim3(N_PTS / IB_BLOCK, JSPLIT), 256, 0, stream>>>(bX, sqX, pdX, piX);
    topk_mfma<32><<<dim3(N_PTS / IB_BLOCK, JSPLIT), 256, 0, stream>>>(bZ, sqZ, pdZ, piZ);
    count_kernel<<<N_PTS / 256, 256, 0, stream>>>(pdX, piX, pdZ, piZ, partial);
    finalize_kernel<<<1, 64, 0, stream>>>(partial, out);
}